// Round 4
// baseline (125.485 us; speedup 1.0000x reference)
//
#include <hip/hip_runtime.h>
#include <math.h>

// ParabolicPool2D: morphological dilation (max-plus pool) with per-channel
// parabolic kernel, KS=7, STRIDE=2, pad=3.
// Key fact: h[c,ki,kj] = g[c,ki] + g[c,kj] with g[c,j] = -z_j^2/(4 t_c)
// => separable max-plus:  out = max_ki( max_kj(f + g_kj) + g_ki ).
//
// Thread tile: 4 outputs wide (wo0 = 4k) x 2 outputs tall (ho0 = 2*ty).
//  - 16 needed input cols [8k-4, 8k+12) = 4 aligned float4 loads per row.
//  - 9 input rows [2*ho0-3, 2*ho0+6) shared between the 2 output rows.
// All loops fully unrolled -> static register indexing (no scratch).

#define KS      7
#define C_CH    96
#define B_SZ    16
#define H_IN    224
#define W_IN    224
#define H_OUT   112
#define W_OUT   112
#define TW      4   // outputs per thread, horizontal
#define KX      (W_OUT / TW)   // 28 horizontal tiles
#define KY      (H_OUT / 2)    // 56 vertical tiles (2 rows per thread)

__global__ __launch_bounds__(256)
void parab_pool2d_kernel(const float* __restrict__ f,
                         const float* __restrict__ t,
                         float* __restrict__ out)
{
    const int idx = blockIdx.x * 256 + threadIdx.x;
    const int total = B_SZ * C_CH * KY * KX;   // 2,408,448
    if (idx >= total) return;

    const int k  = idx % KX;
    const int ty = (idx / KX) % KY;
    const int c  = (idx / (KX * KY)) % C_CH;
    const int b  = idx / (KX * KY * C_CH);

    // Parabolic weights: z = linspace(-2, 3, 7); g[j] = -z^2 / (4 t[c]).
    const float s = 1.0f / (4.0f * t[c]);
    float g[KS];
#pragma unroll
    for (int j = 0; j < KS; ++j) {
        const float z = -2.0f + (float)j * (5.0f / 6.0f);
        g[j] = -(z * z) * s;
    }

    const int wo0     = k * TW;
    const int ho0     = ty * 2;
    const int colbase = 8 * k - 4;     // 16 cols [colbase, colbase+15]
    const int ibase   = 2 * ho0 - 3;   // 9 rows  [ibase, ibase+8]

    const float NEG = -INFINITY;
    const float* __restrict__ plane =
        f + (long)(b * C_CH + c) * (H_IN * W_IN);

    float acc0[TW], acc1[TW];
#pragma unroll
    for (int m = 0; m < TW; ++m) { acc0[m] = NEG; acc1[m] = NEG; }

    const bool interior = (k >= 1) && (k <= KX - 2);

#pragma unroll
    for (int r = 0; r < 9; ++r) {
        const int i = ibase + r;
        if (i < 0 || i >= H_IN) continue;   // out-of-range row == all -inf
        const float* __restrict__ row = plane + (long)i * W_IN;

        float v[16];
        if (interior) {
            const float4* p = (const float4*)(row + colbase);  // 16B aligned
            const float4 a0 = p[0], a1 = p[1], a2 = p[2], a3 = p[3];
            v[0]=a0.x;  v[1]=a0.y;  v[2]=a0.z;  v[3]=a0.w;
            v[4]=a1.x;  v[5]=a1.y;  v[6]=a1.z;  v[7]=a1.w;
            v[8]=a2.x;  v[9]=a2.y;  v[10]=a2.z; v[11]=a2.w;
            v[12]=a3.x; v[13]=a3.y; v[14]=a3.z; v[15]=a3.w;
        } else {
#pragma unroll
            for (int q = 0; q < 16; ++q) {
                const int col = colbase + q;
                v[q] = (col >= 0 && col < W_IN) ? row[col] : NEG;
            }
        }

        // Horizontal max-plus: rm[m] = max_kj( v[2m+1+kj] + g[kj] )
        // (output col wo0+m tap kj reads input col 8k+2m+kj-3 = colbase + 2m+1+kj)
        float rm[TW];
#pragma unroll
        for (int m = 0; m < TW; ++m) {
            float x =       v[2*m + 1] + g[0];
            x = fmaxf(x,    v[2*m + 2] + g[1]);
            x = fmaxf(x,    v[2*m + 3] + g[2]);
            x = fmaxf(x,    v[2*m + 4] + g[3]);
            x = fmaxf(x,    v[2*m + 5] + g[4]);
            x = fmaxf(x,    v[2*m + 6] + g[5]);
            x = fmaxf(x,    v[2*m + 7] + g[6]);
            rm[m] = x;
        }

        // Vertical contribution: out row ho0 uses ki = r (r in 0..6),
        // out row ho0+1 uses ki = r-2 (r in 2..8).
        if (r <= 6) {
#pragma unroll
            for (int m = 0; m < TW; ++m)
                acc0[m] = fmaxf(acc0[m], rm[m] + g[r]);
        }
        if (r >= 2) {
#pragma unroll
            for (int m = 0; m < TW; ++m)
                acc1[m] = fmaxf(acc1[m], rm[m] + g[r - 2]);
        }
    }

    float* __restrict__ orow0 =
        out + ((long)(b * C_CH + c) * H_OUT + ho0) * W_OUT + wo0;
    float* __restrict__ orow1 = orow0 + W_OUT;
    *(float4*)orow0 = make_float4(acc0[0], acc0[1], acc0[2], acc0[3]);
    *(float4*)orow1 = make_float4(acc1[0], acc1[1], acc1[2], acc1[3]);
}

extern "C" void kernel_launch(void* const* d_in, const int* in_sizes, int n_in,
                              void* d_out, int out_size, void* d_ws, size_t ws_size,
                              hipStream_t stream) {
    const float* f = (const float*)d_in[0];   // [16, 96, 224, 224] f32
    const float* t = (const float*)d_in[1];   // [96] f32
    float* out = (float*)d_out;               // [16, 96, 112, 112] f32

    const int total  = B_SZ * C_CH * KY * KX; // 2,408,448 threads
    const int threads = 256;
    const int blocks  = (total + threads - 1) / threads;  // 9408
    parab_pool2d_kernel<<<blocks, threads, 0, stream>>>(f, t, out);
}

// Round 5
// 82.440 us; speedup vs baseline: 1.5221x; 1.5221x over previous
//
#include <hip/hip_runtime.h>
#include <math.h>

// ParabolicPool2D: morphological dilation (max-plus pool), KS=7, STRIDE=2, pad=3.
// Separable in max-plus: h[c,ki,kj] = g[c,ki] + g[c,kj], g[c,j] = -z_j^2/(4 t_c),
// z = linspace(-2, 3, 7)  =>  out = max_ki( max_kj(f + g_kj) + g_ki ).
//
// R5 design: each thread owns a TALL strip — TW=4 output cols x TH=8 output rows,
// rolling vertical window: for each of 21 input rows compute the horizontal
// max-plus rm[4] once, fold it into the <=4 live row-accumulators, emit a
// finished output row every 2 input rows. Vertical row overfetch drops from
// 2.25x (R4: 9 rows read per 4 advanced, cross-wave reuse missed cache) to
// 21/16 = 1.31x, which is per-thread and cache-independent.
//
// Edge tiles (k=0, k=27) use the SAME 4x float4 load path: the one OOB float4
// per side gets a clamped (safe, aligned) address and its value is replaced by
// -inf via cndmask — no divergent scalar-load path (R4 paid 16 guarded scalar
// loads wave-wide per row, every wave).

#define KS     7
#define C_CH   96
#define B_SZ   16
#define H_IN   224
#define W_IN   224
#define H_OUT  112
#define W_OUT  112
#define TW     4                 // output cols per thread
#define TH     8                 // output rows per thread
#define KX     (W_OUT / TW)      // 28
#define KYV    (H_OUT / TH)      // 14
#define NROWS  (2 * TH + 5)      // 21 input rows per strip

__global__ __launch_bounds__(256)
void parab_pool2d_kernel(const float* __restrict__ f,
                         const float* __restrict__ t,
                         float* __restrict__ out)
{
    const int idx = blockIdx.x * 256 + threadIdx.x;
    const int k   = idx % KX;
    const int tyv = (idx / KX) % KYV;
    const int c   = (idx / (KX * KYV)) % C_CH;
    const int b   =  idx / (KX * KYV * C_CH);

    // g[j] = -z_j^2 / (4 t_c),  z = -2 + j*(5/6)
    const float s = 1.0f / (4.0f * t[c]);
    float g[KS];
#pragma unroll
    for (int j = 0; j < KS; ++j) {
        const float z = -2.0f + (float)j * (5.0f / 6.0f);
        g[j] = -(z * z) * s;
    }

    const int wo0     = k * TW;          // first output col
    const int ho0     = tyv * TH;        // first output row
    const int colbase = 2 * wo0 - 4;     // window cols [colbase, colbase+15]
    const int ibase   = 2 * ho0 - 3;     // input rows [ibase, ibase+20]

    const float  NEG = -INFINITY;
    const float4 N4  = make_float4(NEG, NEG, NEG, NEG);

    const float* __restrict__ plane = f + (b * C_CH + c) * (H_IN * W_IN);
    float* __restrict__ obase =
        out + ((b * C_CH + c) * H_OUT + ho0) * W_OUT + wo0;

    // Per-lane safe sub-offsets for the two possibly-OOB float4s.
    const bool kzero = (k == 0);          // cols -4..-1 invalid -> a0 = -inf
    const bool klast = (k == KX - 1);     // cols 224..227 invalid -> a3 = -inf
    const int  off0  = kzero ? 4 : 0;     // a0 loads cols colbase+off0.. (aligned, in-bounds)
    const int  off3  = klast ? 8 : 12;

    float acc[TH][TW];
#pragma unroll
    for (int d = 0; d < TH; ++d)
#pragma unroll
        for (int m = 0; m < TW; ++m) acc[d][m] = NEG;

#pragma unroll
    for (int r = 0; r < NROWS; ++r) {      // fully unrolled: all indices static
        const int  i     = ibase + r;
        const bool rowok = (i >= 0) && (i < H_IN);
        const int  isafe = rowok ? i : 0;  // safe row for masked-out loads
        const float* rb  = plane + isafe * W_IN + colbase;

        float4 a0 = *(const float4*)(rb + off0);
        float4 a1 = *(const float4*)(rb + 4);
        float4 a2 = *(const float4*)(rb + 8);
        float4 a3 = *(const float4*)(rb + off3);
        if (kzero) a0 = N4;                // cndmask fixups, no divergence cost
        if (klast) a3 = N4;

        const float v[16] = {a0.x,a0.y,a0.z,a0.w, a1.x,a1.y,a1.z,a1.w,
                             a2.x,a2.y,a2.z,a2.w, a3.x,a3.y,a3.z,a3.w};

        // Horizontal max-plus: rm[m] = max_j( v[2m+1+j] + g[j] ), j=0..6
        float rm[TW];
#pragma unroll
        for (int m = 0; m < TW; ++m) {
            float x =    v[2*m + 1] + g[0];
            x = fmaxf(x, v[2*m + 2] + g[1]);
            x = fmaxf(x, v[2*m + 3] + g[2]);
            x = fmaxf(x, v[2*m + 4] + g[3]);
            x = fmaxf(x, v[2*m + 5] + g[4]);
            x = fmaxf(x, v[2*m + 6] + g[5]);
            x = fmaxf(x, v[2*m + 7] + g[6]);
            rm[m] = rowok ? x : NEG;       // -inf row: updates become no-ops
        }

        // Vertical rolling update: output row d uses ki = r - 2d in [0,6].
#pragma unroll
        for (int d = 0; d < TH; ++d) {
            if (r >= 2 * d && r <= 2 * d + 6) {
#pragma unroll
                for (int m = 0; m < TW; ++m)
                    acc[d][m] = fmaxf(acc[d][m], rm[m] + g[r - 2 * d]);
            }
        }

        // Row d is complete after r = 2d+6 -> emit (spreads stores through loop).
        if (r >= 6 && ((r - 6) & 1) == 0) {
            const int d = (r - 6) / 2;     // compile-time after unroll
            *(float4*)(obase + d * W_OUT) =
                make_float4(acc[d][0], acc[d][1], acc[d][2], acc[d][3]);
        }
    }
}

extern "C" void kernel_launch(void* const* d_in, const int* in_sizes, int n_in,
                              void* d_out, int out_size, void* d_ws, size_t ws_size,
                              hipStream_t stream) {
    const float* f = (const float*)d_in[0];   // [16, 96, 224, 224] f32
    const float* t = (const float*)d_in[1];   // [96] f32
    float* out = (float*)d_out;               // [16, 96, 112, 112] f32

    const int total   = B_SZ * C_CH * KYV * KX;  // 602,112 threads
    const int threads = 256;
    const int blocks  = total / threads;         // 2352, exact
    parab_pool2d_kernel<<<blocks, threads, 0, stream>>>(f, t, out);
}